// Round 1
// baseline (1469.491 us; speedup 1.0000x reference)
//
#include <hip/hip_runtime.h>

// ---------------------------------------------------------------------------
// EquivariantConvExp: z -> tanh(conv_exp(z, k_i)) for i = 3,2,1,0
// conv_exp = sum_{n=0..10} K^n z / n!   (7x7 'same' cross-correlation, C=1)
// log_det  = -(H*W) * sum_i k_i[center]
//
// Design: per-image line-buffer cascade. 11 waves/block:
//   waves 0..9  = series stages (stage n = wave+1), lag 4 rows per stage
//   wave 10     = loader (z row t) + acc init + tanh finalize + store
// LDS: 10 input rings (7 rows each, f16, 4-elem zero margins) + 42-row f16 acc.
// Math: v_dot2_f32_f16 (2 MAC/instr, fp32 accumulate).
// ---------------------------------------------------------------------------

typedef _Float16 h2 __attribute__((ext_vector_type(2)));

#define HH 256
#define WW 256
#define NT 10                      // series terms
#define NRINGS 10                  // I_0..I_9 (prod_10 feeds only acc)
#define PITCH 264                  // u16 per ring row: 4 margin + 256 + 4 margin
#define RING_ELEMS (PITCH * 7)     // 1848
#define ACCE (NRINGS * RING_ELEMS) // 18480
#define ACC_ROWS 42
#define SMEM_U16 (ACCE + ACC_ROWS * WW) // 29232 u16 = 58464 B
#define FIN_LAG (4 * NT + 1)       // 41
#define T_STEPS (HH + FIN_LAG)     // 297
#define NTHREADS 704

union U32H2 { unsigned int u; h2 h; };
__device__ __forceinline__ h2 uh(unsigned int u) { U32H2 x; x.u = u; return x.h; }
__device__ __forceinline__ unsigned int hu(h2 h) { U32H2 x; x.h = h; return x.u; }
__device__ __forceinline__ unsigned int pk2f(float lo, float hi) {
    h2 h; h[0] = (_Float16)lo; h[1] = (_Float16)hi; return hu(h);
}

__device__ __forceinline__ float dot2f(unsigned int a, unsigned int b, float c) {
#if __has_builtin(__builtin_amdgcn_fdot2)
    return __builtin_amdgcn_fdot2(uh(a), uh(b), c, false);
#else
    h2 ah = uh(a), bh = uh(b);
    return c + (float)ah[0] * (float)bh[0] + (float)ah[1] * (float)bh[1];
#endif
}

__device__ __forceinline__ float tanh_fast(float x) {
    float e = __expf(2.0f * x);
    return 1.0f - 2.0f / (e + 1.0f);   // inf-safe: x>>0 -> 1, x<<0 -> -1
}

// Packed per-row kernel taps (8 u32 per ky):
//  [0]=(0,w0) [1]=(w1,w2) [2]=(w3,w4) [3]=(w5,w6)   (even output cols)
//  [4]=(w0,w1) [5]=(w2,w3) [6]=(w4,w5) [7]=(w6,0)   (odd  output cols)
__global__ void prep_kernel(const float* __restrict__ filters,
                            float* __restrict__ logdet,
                            unsigned int* __restrict__ pk) {
    const int tid = threadIdx.x;
    if (tid < 28) {
        const int blk = tid / 7, ky = tid - blk * 7;
        const float* w = filters + blk * 49 + ky * 7;
        unsigned int* o = pk + blk * 64 + ky * 8;
        o[0] = pk2f(0.f, w[0]);  o[1] = pk2f(w[1], w[2]);
        o[2] = pk2f(w[3], w[4]); o[3] = pk2f(w[5], w[6]);
        o[4] = pk2f(w[0], w[1]); o[5] = pk2f(w[2], w[3]);
        o[6] = pk2f(w[4], w[5]); o[7] = pk2f(w[6], 0.f);
    }
    const float c = -(float)(HH * WW) *
        (filters[24] + filters[49 + 24] + filters[98 + 24] + filters[147 + 24]);
    for (int j = tid; j < 256; j += blockDim.x) logdet[j] = c;
}

template <int IN_F16, int OUT_F16>
__global__ __launch_bounds__(NTHREADS)
void cascade_kernel(const void* __restrict__ in_, void* __restrict__ out_,
                    const unsigned int* __restrict__ pkg) {
    __shared__ __align__(16) unsigned short smem[SMEM_U16];
    const int tid = threadIdx.x;
    const int wav = tid >> 6;
    const int lane = tid & 63;
    const int img = blockIdx.x;

    { // zero LDS (margins + initial ring/acc state must be 0)
        unsigned int* s4 = (unsigned int*)smem;
        for (int i = tid; i < SMEM_U16 / 2; i += NTHREADS) s4[i] = 0u;
    }

    unsigned int Kc[56];
#pragma unroll
    for (int i = 0; i < 56; ++i)
        Kc[i] = __builtin_amdgcn_readfirstlane(pkg[i]);
    __syncthreads();

    const bool is_stage = (wav < NT);
    const int stg = wav + 1;                      // 1..10 for stage waves
    const float sinv = 1.0f / (float)stg;
    const int rb_in = wav * RING_ELEMS;           // input ring I_{stg-1}
    const int rb_out = (wav + 1) * RING_ELEMS;    // output ring I_stg (stg<NT only)
    const bool is_util = (wav == NT);

    const unsigned short* gin16 = (const unsigned short*)in_ + (size_t)img * (HH * WW);
    const float* gin32 = (const float*)in_ + (size_t)img * (HH * WW);
    unsigned short* gout16 = (unsigned short*)out_ + (size_t)img * (HH * WW);
    float* gout32 = (float*)out_ + (size_t)img * (HH * WW);

    for (int t = 0; t < T_STEPS; ++t) {
        // ----------------- phase A: LDS/global reads + compute -----------------
        float o0 = 0.f, o1 = 0.f, o2 = 0.f, o3 = 0.f;
        const int q = t - 4 * stg;                 // output row of this stage
        const bool act = is_stage && (q >= 0) && (q < HH);

        if (act) {
            const int m0 = (int)((unsigned)(q + 4) % 7u); // slot of row q-3
#pragma unroll
            for (int ky = 0; ky < 7; ++ky) {
                int s = m0 + ky; if (s >= 7) s -= 7;      // slot of row q+ky-3
                const uint2* p = (const uint2*)&smem[rb_in + s * PITCH + 4 * lane];
                const uint2 A = p[0], B = p[1], C = p[2];
                const unsigned int v0 = A.x, v1 = A.y, v2 = B.x,
                                   v3 = B.y, v4 = C.x, v5 = C.y;
                const unsigned int P0 = Kc[ky * 8 + 0], P1 = Kc[ky * 8 + 1],
                                   P2 = Kc[ky * 8 + 2], P3 = Kc[ky * 8 + 3],
                                   P4 = Kc[ky * 8 + 4], P5 = Kc[ky * 8 + 5],
                                   P6 = Kc[ky * 8 + 6], P7 = Kc[ky * 8 + 7];
                o0 = dot2f(v0, P0, o0); o0 = dot2f(v1, P1, o0);
                o0 = dot2f(v2, P2, o0); o0 = dot2f(v3, P3, o0);
                o1 = dot2f(v1, P4, o1); o1 = dot2f(v2, P5, o1);
                o1 = dot2f(v3, P6, o1); o1 = dot2f(v4, P7, o1);
                o2 = dot2f(v1, P0, o2); o2 = dot2f(v2, P1, o2);
                o2 = dot2f(v3, P2, o2); o2 = dot2f(v4, P3, o2);
                o3 = dot2f(v2, P4, o3); o3 = dot2f(v3, P5, o3);
                o3 = dot2f(v4, P6, o3); o3 = dot2f(v5, P7, o3);
            }
            o0 *= sinv; o1 *= sinv; o2 *= sinv; o3 *= sinv;
        }

        float z0 = 0, z1 = 0, z2 = 0, z3 = 0;
        const bool do_load = is_util && (t < HH);
        if (do_load) {
            if (IN_F16) {
                const uint2 g = *(const uint2*)(gin16 + t * WW + 4 * lane);
                const h2 a = uh(g.x), b = uh(g.y);
                z0 = (float)a[0]; z1 = (float)a[1]; z2 = (float)b[0]; z3 = (float)b[1];
            } else {
                const float4 g = *(const float4*)(gin32 + t * WW + 4 * lane);
                z0 = g.x; z1 = g.y; z2 = g.z; z3 = g.w;
            }
        }

        const int f = t - FIN_LAG;
        const bool do_fin = is_util && (f >= 0);
        float t0 = 0, t1 = 0, t2 = 0, t3 = 0;
        if (do_fin) {
            const int arow = (int)((unsigned)f % (unsigned)ACC_ROWS);
            const uint2 av = *(const uint2*)&smem[ACCE + arow * WW + 4 * lane];
            const h2 a = uh(av.x), b = uh(av.y);
            t0 = tanh_fast((float)a[0]); t1 = tanh_fast((float)a[1]);
            t2 = tanh_fast((float)b[0]); t3 = tanh_fast((float)b[1]);
        }

        __syncthreads();

        // ----------------- phase B: LDS/global writes -----------------
        if (is_stage) {
            if (q >= 0 && q < HH) {
                if (stg < NT) { // prod row -> ring I_stg
                    uint2 w; w.x = pk2f(o0, o1); w.y = pk2f(o2, o3);
                    *(uint2*)&smem[rb_out + (int)((unsigned)q % 7u) * PITCH + 4 + 4 * lane] = w;
                }
                // acc[q] += prod (packed f16 add)
                unsigned short* ap = &smem[ACCE + (int)((unsigned)q % (unsigned)ACC_ROWS) * WW + 4 * lane];
                uint2 av = *(const uint2*)ap;
                h2 lo = uh(av.x), hi = uh(av.y);
                h2 plo, phi;
                plo[0] = (_Float16)o0; plo[1] = (_Float16)o1;
                phi[0] = (_Float16)o2; phi[1] = (_Float16)o3;
                lo = lo + plo; hi = hi + phi;
                uint2 nv; nv.x = hu(lo); nv.y = hu(hi);
                *(uint2*)ap = nv;
            } else if (q >= HH && q <= HH + 2 && stg < NT) {
                // top boundary rows must read as zero next stage
                uint2 w; w.x = 0u; w.y = 0u;
                *(uint2*)&smem[rb_out + (int)((unsigned)(q + 7) % 7u) * PITCH + 4 + 4 * lane] = w;
            }
        } else if (is_util) {
            if (t < HH) {
                uint2 w; w.x = pk2f(z0, z1); w.y = pk2f(z2, z3);
                *(uint2*)&smem[(int)((unsigned)t % 7u) * PITCH + 4 + 4 * lane] = w;        // ring 0 (z)
                *(uint2*)&smem[ACCE + (int)((unsigned)t % (unsigned)ACC_ROWS) * WW + 4 * lane] = w; // acc init = z
            } else if (t <= HH + 2) {
                uint2 w; w.x = 0u; w.y = 0u;
                *(uint2*)&smem[(int)((unsigned)t % 7u) * PITCH + 4 + 4 * lane] = w;
            }
            if (do_fin) {
                if (OUT_F16) {
                    uint2 w; w.x = pk2f(t0, t1); w.y = pk2f(t2, t3);
                    *(uint2*)(gout16 + f * WW + 4 * lane) = w;
                } else {
                    float4 w; w.x = t0; w.y = t1; w.z = t2; w.w = t3;
                    *(float4*)(gout32 + f * WW + 4 * lane) = w;
                }
            }
        }
        __syncthreads();
    }
}

extern "C" void kernel_launch(void* const* d_in, const int* in_sizes, int n_in,
                              void* d_out, int out_size, void* d_ws, size_t ws_size,
                              hipStream_t stream) {
    (void)in_sizes; (void)n_in; (void)out_size; (void)ws_size;
    const float* x = (const float*)d_in[0];
    const float* fl = (const float*)d_in[1];
    float* out = (float*)d_out;
    float* logdet = out + (size_t)256 * 256 * 256;

    // f16 ping buffers: A in workspace, B aliases d_out's z region (safe: z is
    // written fp32 only by the final block, after B has been consumed).
    unsigned short* bufA = (unsigned short*)d_ws;
    unsigned short* bufB = (unsigned short*)d_out;
    unsigned int* pk = (unsigned int*)((char*)d_ws + (size_t)256 * 256 * 256 * 2);

    prep_kernel<<<1, 64, 0, stream>>>(fl, logdet, pk);
    // blocks applied in reversed order: filters[3], [2], [1], [0]
    cascade_kernel<0, 1><<<256, NTHREADS, 0, stream>>>(x,    bufA, pk + 3 * 64);
    cascade_kernel<1, 1><<<256, NTHREADS, 0, stream>>>(bufA, bufB, pk + 2 * 64);
    cascade_kernel<1, 1><<<256, NTHREADS, 0, stream>>>(bufB, bufA, pk + 1 * 64);
    cascade_kernel<1, 0><<<256, NTHREADS, 0, stream>>>(bufA, out,  pk + 0 * 64);
}

// Round 3
// 968.593 us; speedup vs baseline: 1.5171x; 1.5171x over previous
//
#include <hip/hip_runtime.h>

// ---------------------------------------------------------------------------
// EquivariantConvExp: z -> tanh(conv_exp(z, k_i)) for i = 3,2,1,0
// conv_exp = sum_{n=0..10} K^n z / n!   (7x7 'same' cross-correlation, C=1)
// log_det  = -(H*W) * sum_i k_i[center]
//
// R3 == R2 resubmitted (R2 bench died to container-acquisition infra failure,
// not a kernel failure). Register-window line-buffer cascade. 11 waves/block:
//   waves 0..9 = series stages (stage n = wave+1), lag 4 rows/stage;
//   wave 10    = loader (PF=3-step global prefetch) + acc init + tanh + store.
// Each stage keeps its 7-row input window IN REGISTERS (42 VGPR); per step it
// reads only the one newly-produced row from LDS (3x ds_read_b64). t-loop is
// unrolled x7 so ring slots / window rotation are compile-time; acc rows use
// incremental wrapping pointers (no modulo). Cross-wave LDS touches per step
// are all to distinct rows/slots -> ONE barrier per step.
// ---------------------------------------------------------------------------

typedef _Float16 h2 __attribute__((ext_vector_type(2)));

#define HH 256
#define WW 256
#define NT 10                      // series terms
#define NRINGS 10                  // interfaces I_0..I_9
#define PITCH 264                  // u16 per ring row: 4 margin + 256 + 4 margin
#define RING_ELEMS (PITCH * 7)
#define ACCE (NRINGS * RING_ELEMS) // 18480 u16
#define ACC_ROWS 42
#define SMEM_U16 (ACCE + ACC_ROWS * WW) // 29232 u16 = 58464 B
#define FIN_LAG 41                 // 4*NT + 1
#define T_STEPS 301                // 43*7 >= 297 needed steps
#define NTHREADS 704
#define PF 3                       // global-load prefetch depth (steps)

union U32H2 { unsigned int u; h2 h; };
static __device__ __forceinline__ h2 uh(unsigned int u) { U32H2 x; x.u = u; return x.h; }
static __device__ __forceinline__ unsigned int hu(h2 h) { U32H2 x; x.h = h; return x.u; }
static __device__ __forceinline__ unsigned int pk2f(float lo, float hi) {
    h2 h; h[0] = (_Float16)lo; h[1] = (_Float16)hi; return hu(h);
}

static __device__ __forceinline__ float dot2f(unsigned int a, unsigned int b, float c) {
#if __has_builtin(__builtin_amdgcn_fdot2)
    return __builtin_amdgcn_fdot2(uh(a), uh(b), c, false);
#else
    h2 ah = uh(a), bh = uh(b);
    return c + (float)ah[0] * (float)bh[0] + (float)ah[1] * (float)bh[1];
#endif
}

static __device__ __forceinline__ float tanh_fast(float x) {
    float e = __expf(2.0f * x);
    return 1.0f - 2.0f / (e + 1.0f);   // inf-safe
}

// Packed per-row kernel taps (8 u32 per ky):
//  [0]=(0,w0) [1]=(w1,w2) [2]=(w3,w4) [3]=(w5,w6)   (even output cols)
//  [4]=(w0,w1) [5]=(w2,w3) [6]=(w4,w5) [7]=(w6,0)   (odd  output cols)
__global__ void prep_kernel(const float* __restrict__ filters,
                            float* __restrict__ logdet,
                            unsigned int* __restrict__ pk) {
    const int tid = threadIdx.x;
    if (tid < 28) {
        const int blk = tid / 7, ky = tid - blk * 7;
        const float* w = filters + blk * 49 + ky * 7;
        unsigned int* o = pk + blk * 64 + ky * 8;
        o[0] = pk2f(0.f, w[0]);  o[1] = pk2f(w[1], w[2]);
        o[2] = pk2f(w[3], w[4]); o[3] = pk2f(w[5], w[6]);
        o[4] = pk2f(w[0], w[1]); o[5] = pk2f(w[2], w[3]);
        o[6] = pk2f(w[4], w[5]); o[7] = pk2f(w[6], 0.f);
    }
    const float c = -(float)(HH * WW) *
        (filters[24] + filters[49 + 24] + filters[98 + 24] + filters[147 + 24]);
    for (int j = tid; j < 256; j += blockDim.x) logdet[j] = c;
}

template <int IN_F16, int OUT_F16>
__global__ __launch_bounds__(NTHREADS)
void cascade_kernel(const void* __restrict__ in_, void* __restrict__ out_,
                    const unsigned int* __restrict__ pkg) {
    __shared__ __align__(16) unsigned short smem[SMEM_U16];
    const int tid = threadIdx.x;
    const int wav = tid >> 6;
    const int lane = tid & 63;
    const int img = blockIdx.x;

    { // zero LDS (margins + initial ring/acc state must be 0)
        unsigned int* s4 = (unsigned int*)smem;
        for (int i = tid; i < SMEM_U16 / 2; i += NTHREADS) s4[i] = 0u;
    }

    unsigned int Kc[56];
#pragma unroll
    for (int i = 0; i < 56; ++i)
        Kc[i] = __builtin_amdgcn_readfirstlane(pkg[i]);   // lives in SGPRs

    const bool is_stage = (wav < NT);
    const bool is_util = (wav == NT);
    const int stg = wav + 1;                 // 1..10 for stage waves
    const float sinv = 1.0f / (float)stg;
    const int rb_in = wav * RING_ELEMS;      // input ring I_{stg-1}
    const int rb_out = (wav + 1) * RING_ELEMS; // output ring I_stg (stg<NT only)

    // Precomputed per-unroll-slot LDS indices (u16 units). t0 % 7 == 0 always,
    // so ring slot depends only on u (compile-time) + per-wave constant.
    int rdIdx[7], wrIdx[7];
#pragma unroll
    for (int u = 0; u < 7; ++u) {
        const int sR = (((u + 3 - 4 * stg) % 7) + 7) % 7;  // slot of row q+3
        const int sW = (((u - 4 * stg) % 7) + 7) % 7;      // slot of row q
        rdIdx[u] = rb_in + sR * PITCH + 4 * lane;          // halo read (payload-4)
        wrIdx[u] = rb_out + sW * PITCH + 4 + 4 * lane;     // payload write
    }

    // 7-row register window; age j at unroll-step u lives in slot (u+j)%7.
    // Zero-init => rows < 0 read as zero (priming).
    unsigned int win[7][6];
#pragma unroll
    for (int a = 0; a < 7; ++a)
#pragma unroll
        for (int b = 0; b < 6; ++b) win[a][b] = 0u;

    // Incremental wrapping acc-row pointers (row = (t - X) mod 42 at step t).
    const int ACC_END = ACCE + ACC_ROWS * WW;
    int accS = ACCE + ((((-4 * stg) % ACC_ROWS) + ACC_ROWS) % ACC_ROWS) * WW + 4 * lane;
    int accI = ACCE + 4 * lane;              // util z-init row t
    int accF = ACCE + 1 * WW + 4 * lane;     // util finalize row t-41

    const unsigned short* gin16 = (const unsigned short*)in_ + (size_t)img * (HH * WW);
    const float* gin32 = (const float*)in_ + (size_t)img * (HH * WW);
    unsigned short* gout16 = (unsigned short*)out_ + (size_t)img * (HH * WW);
    float* gout32 = (float*)out_ + (size_t)img * (HH * WW);

    // z-row prefetch registers (row r sits in slot r%7; loaded PF steps early)
    uint2 zh[7]; float4 zf[7];
    if (is_util) {
#pragma unroll
        for (int r = 0; r < PF; ++r) {
            if (IN_F16) zh[r] = *(const uint2*)(gin16 + r * WW + 4 * lane);
            else        zf[r] = *(const float4*)(gin32 + r * WW + 4 * lane);
        }
    }
    __syncthreads();

    for (int t0 = 0; t0 < T_STEPS; t0 += 7) {
#pragma unroll
        for (int u = 0; u < 7; ++u) {
            const int t = t0 + u;
            if (is_stage) {
                const int q = t - 4 * stg;         // output row of this stage
                { // pull the newly-available row (q+3) into window age-6 slot
                    const uint2* p = (const uint2*)&smem[rdIdx[u]];
                    const uint2 A = p[0], B = p[1], C = p[2];
                    win[(u + 6) % 7][0] = A.x; win[(u + 6) % 7][1] = A.y;
                    win[(u + 6) % 7][2] = B.x; win[(u + 6) % 7][3] = B.y;
                    win[(u + 6) % 7][4] = C.x; win[(u + 6) % 7][5] = C.y;
                }
                if (q >= 0 && q < HH) {
                    float o0 = 0.f, o1 = 0.f, o2 = 0.f, o3 = 0.f;
#pragma unroll
                    for (int ky = 0; ky < 7; ++ky) {
                        const unsigned int v0 = win[(u + ky) % 7][0], v1 = win[(u + ky) % 7][1],
                                           v2 = win[(u + ky) % 7][2], v3 = win[(u + ky) % 7][3],
                                           v4 = win[(u + ky) % 7][4], v5 = win[(u + ky) % 7][5];
                        const unsigned int P0 = Kc[ky * 8 + 0], P1 = Kc[ky * 8 + 1],
                                           P2 = Kc[ky * 8 + 2], P3 = Kc[ky * 8 + 3],
                                           P4 = Kc[ky * 8 + 4], P5 = Kc[ky * 8 + 5],
                                           P6 = Kc[ky * 8 + 6], P7 = Kc[ky * 8 + 7];
                        o0 = dot2f(v0, P0, o0); o0 = dot2f(v1, P1, o0);
                        o0 = dot2f(v2, P2, o0); o0 = dot2f(v3, P3, o0);
                        o1 = dot2f(v1, P4, o1); o1 = dot2f(v2, P5, o1);
                        o1 = dot2f(v3, P6, o1); o1 = dot2f(v4, P7, o1);
                        o2 = dot2f(v1, P0, o2); o2 = dot2f(v2, P1, o2);
                        o2 = dot2f(v3, P2, o2); o2 = dot2f(v4, P3, o2);
                        o3 = dot2f(v2, P4, o3); o3 = dot2f(v3, P5, o3);
                        o3 = dot2f(v4, P6, o3); o3 = dot2f(v5, P7, o3);
                    }
                    o0 *= sinv; o1 *= sinv; o2 *= sinv; o3 *= sinv;
                    uint2 w; w.x = pk2f(o0, o1); w.y = pk2f(o2, o3);
                    if (stg < NT) *(uint2*)&smem[wrIdx[u]] = w;   // hand-off row q
                    // acc[q] += prod (f16 packed RMW; only this wave touches row q this step)
                    const uint2 av = *(const uint2*)&smem[accS];
                    const h2 lo = uh(av.x) + uh(w.x), hi = uh(av.y) + uh(w.y);
                    uint2 nv; nv.x = hu(lo); nv.y = hu(hi);
                    *(uint2*)&smem[accS] = nv;
                } else if (q >= HH && q <= HH + 2 && stg < NT) {
                    // bottom boundary rows must read as zero downstream
                    uint2 w; w.x = 0u; w.y = 0u;
                    *(uint2*)&smem[wrIdx[u]] = w;
                }
                accS += WW; if (accS >= ACC_END) accS -= ACC_ROWS * WW;
            } else if (is_util) {
                // issue global load for row t+PF (consumed PF steps later)
                if (t + PF < HH) {
                    if (IN_F16) zh[(u + PF) % 7] = *(const uint2*)(gin16 + (size_t)(t + PF) * WW + 4 * lane);
                    else        zf[(u + PF) % 7] = *(const float4*)(gin32 + (size_t)(t + PF) * WW + 4 * lane);
                }
                // write row t (z) to ring0 + acc init; zeros for boundary rows
                if (t <= HH + 2) {
                    uint2 w;
                    if (t < HH) {
                        if (IN_F16) w = zh[u];
                        else { const float4 g = zf[u]; w.x = pk2f(g.x, g.y); w.y = pk2f(g.z, g.w); }
                    } else { w.x = 0u; w.y = 0u; }
                    *(uint2*)&smem[u * PITCH + 4 + 4 * lane] = w;  // ring0 slot t%7 == u
                    if (t < HH) *(uint2*)&smem[accI] = w;          // acc init = z
                }
                // finalize row f = t - 41: tanh + store
                const int f = t - FIN_LAG;
                if (f >= 0 && f < HH) {
                    const uint2 av = *(const uint2*)&smem[accF];
                    const h2 a = uh(av.x), b = uh(av.y);
                    const float r0 = tanh_fast((float)a[0]), r1 = tanh_fast((float)a[1]);
                    const float r2 = tanh_fast((float)b[0]), r3 = tanh_fast((float)b[1]);
                    if (OUT_F16) {
                        uint2 w; w.x = pk2f(r0, r1); w.y = pk2f(r2, r3);
                        *(uint2*)(gout16 + (size_t)f * WW + 4 * lane) = w;
                    } else {
                        float4 w; w.x = r0; w.y = r1; w.z = r2; w.w = r3;
                        *(float4*)(gout32 + (size_t)f * WW + 4 * lane) = w;
                    }
                }
                accI += WW; if (accI >= ACC_END) accI -= ACC_ROWS * WW;
                accF += WW; if (accF >= ACC_END) accF -= ACC_ROWS * WW;
            }
            // Single barrier: within a step every wave touches distinct LDS
            // rows/slots; producer->consumer hand-off crosses exactly one barrier.
            __syncthreads();
        }
    }
}

extern "C" void kernel_launch(void* const* d_in, const int* in_sizes, int n_in,
                              void* d_out, int out_size, void* d_ws, size_t ws_size,
                              hipStream_t stream) {
    (void)in_sizes; (void)n_in; (void)out_size; (void)ws_size;
    const float* x = (const float*)d_in[0];
    const float* fl = (const float*)d_in[1];
    float* out = (float*)d_out;
    float* logdet = out + (size_t)256 * 256 * 256;

    // f16 ping buffers: A in workspace, B aliases d_out's z region (safe: z is
    // written fp32 only by the final block, after B has been consumed).
    unsigned short* bufA = (unsigned short*)d_ws;
    unsigned short* bufB = (unsigned short*)d_out;
    unsigned int* pk = (unsigned int*)((char*)d_ws + (size_t)256 * 256 * 256 * 2);

    prep_kernel<<<1, 64, 0, stream>>>(fl, logdet, pk);
    // blocks applied in reversed order: filters[3], [2], [1], [0]
    cascade_kernel<0, 1><<<256, NTHREADS, 0, stream>>>(x,    bufA, pk + 3 * 64);
    cascade_kernel<1, 1><<<256, NTHREADS, 0, stream>>>(bufA, bufB, pk + 2 * 64);
    cascade_kernel<1, 1><<<256, NTHREADS, 0, stream>>>(bufB, bufA, pk + 1 * 64);
    cascade_kernel<1, 0><<<256, NTHREADS, 0, stream>>>(bufA, out,  pk + 0 * 64);
}